// Round 1
// baseline (380.702 us; speedup 1.0000x reference)
//
#include <hip/hip_runtime.h>

#define M_DIM 16384
#define N_DIM 2048
#define K_DIM 2048
#define KB    (K_DIM / 128)

// GEMM geometry: 256x256 tile, BK=64, 8 waves (2M x 4N), double-buffered 128 KiB LDS
#define BM 256
#define BN 256
#define BK 64
#define NT (K_DIM / BK)   // 32 K-tiles

// quant grid partition: 256 threads x 4 floats per block
#define XGRID (M_DIM * K_DIM / 1024)   // 32768
#define WGRID (N_DIM * K_DIM / 1024)   // 4096

typedef __bf16 bf16x8 __attribute__((ext_vector_type(8)));
typedef float  f32x4  __attribute__((ext_vector_type(4)));

__device__ __forceinline__ unsigned short f32_to_bf16_rne(float f) {
    unsigned int u = __float_as_uint(f);
    u += 0x7FFFu + ((u >> 16) & 1u);
    return (unsigned short)(u >> 16);
}

// ---- Fused pass: activation quant+dequant (blocks [0,XGRID)) and weight dequant ----
__global__ __launch_bounds__(256) void quant_all_kernel(const float* __restrict__ x,
                                                        unsigned short* __restrict__ xdq,
                                                        const float* __restrict__ w,
                                                        const float* __restrict__ wscale,
                                                        unsigned short* __restrict__ wdq) {
    const int tid = threadIdx.x;
    if (blockIdx.x < XGRID) {
        // 32 consecutive lanes (half-wave) cover one 128-elem K-block
        const size_t base = ((size_t)blockIdx.x * 256 + tid) * 4;
        const float4 v = *(const float4*)(x + base);
        float amax = fmaxf(fmaxf(fabsf(v.x), fabsf(v.y)), fmaxf(fabsf(v.z), fabsf(v.w)));
#pragma unroll
        for (int m = 16; m >= 1; m >>= 1)
            amax = fmaxf(amax, __shfl_xor(amax, m, 64));
        float s = amax / 448.0f;                  // true f32 div (matches reference)
        if (s == 0.0f) s = 1.0f;
        const int p01 = __builtin_amdgcn_cvt_pk_fp8_f32(v.x / s, v.y / s, 0, false);
        const int p23 = __builtin_amdgcn_cvt_pk_fp8_f32(v.z / s, v.w / s, 0, false);
        const float d0 = __builtin_amdgcn_cvt_f32_fp8(p01, 0) * s;
        const float d1 = __builtin_amdgcn_cvt_f32_fp8(p01, 1) * s;
        const float d2 = __builtin_amdgcn_cvt_f32_fp8(p23, 0) * s;
        const float d3 = __builtin_amdgcn_cvt_f32_fp8(p23, 1) * s;
        uint2 out;
        out.x = (unsigned int)f32_to_bf16_rne(d0) | ((unsigned int)f32_to_bf16_rne(d1) << 16);
        out.y = (unsigned int)f32_to_bf16_rne(d2) | ((unsigned int)f32_to_bf16_rne(d3) << 16);
        *(uint2*)(xdq + base) = out;
    } else {
        const size_t e = ((size_t)(blockIdx.x - XGRID) * 256 + tid) * 4;
        const float4 v = *(const float4*)(w + e);
        const int n = (int)(e >> 11);
        const int k = (int)(e & 2047);
        const float s = wscale[(n >> 7) * KB + (k >> 7)];   // k..k+3 same 128-block
        uint2 out;
        out.x = (unsigned int)f32_to_bf16_rne(v.x * s) | ((unsigned int)f32_to_bf16_rne(v.y * s) << 16);
        out.y = (unsigned int)f32_to_bf16_rne(v.z * s) | ((unsigned int)f32_to_bf16_rne(v.w * s) << 16);
        *(uint2*)(wdq + e) = out;
    }
}

// ---- GEMM: C = A @ B^T, bf16 in, f32 out. 256x256 tile, 8-phase counted-vmcnt schedule ----
//
// Schedule (4 phases per K-tile, one output quadrant each; tile t read from buf[t&1]):
//   stage order for tile t+1 (8 global_load_lds per wave): ph0: B0,B1,B2  ph1: B3,A0,A2
//   ph2: A1,A3  ph3: -.  Phase p of the NEXT tile needs: ph0: {B0..B3,A0,A2} (loads 1-6),
//   ph2: {A1,A3} (loads 7-8).  Steady-state waits (after MFMA, before closing barrier):
//   end-ph1: vmcnt(6)  [retires prev tile's A1,A3; 6 current-stage loads in flight]
//   end-ph3: vmcnt(2)  [retires next tile's loads 1-6; leaves A1,A3 in flight]
//   Raw s_barrier everywhere — __syncthreads() would drain vmcnt(0) (the m97 stall).
// LDS swizzle: physical chunk (row,c) holds logical (row, c ^ (row&7)); staging permutes
// the per-lane GLOBAL source (global_load_lds dest must stay lane-linear), reads XOR.
__global__ __launch_bounds__(512, 2) void gemm_bt_kernel(const unsigned short* __restrict__ A,
                                                         const unsigned short* __restrict__ B,
                                                         float* __restrict__ C) {
    __shared__ __align__(16) unsigned short As[2][BM * BK];   // 64 KiB
    __shared__ __align__(16) unsigned short Bs[2][BN * BK];   // 64 KiB

    const int tid  = threadIdx.x;
    const int lane = tid & 63;
    const int wave = tid >> 6;
    const int wm   = (wave >> 2) * 128;   // 2 waves along M -> per-wave 128 rows
    const int wn   = (wave & 3) * 64;     // 4 waves along N -> per-wave 64 cols
    const int quad = lane >> 4;
    const int l16  = lane & 15;

    // grid: x carries M so XCD round-robin partitions A-slabs (proven layout)
    const int m0 = blockIdx.x * BM;
    const int n0 = blockIdx.y * BN;

    f32x4 acc[8][4] = {};

    // Staging: one global_load_lds = 512 lanes x 16B = 8 KiB = 64 rows of [*][BK].
    // Lane covers row = i*64 + (tid>>3), physical chunk tid&7, source chunk XOR-swizzled.
    const int srow = tid >> 3;                    // 0..63
    const int scol = (tid & 7) ^ (srow & 7);
    const unsigned short* gA = A + (size_t)(m0 + srow) * K_DIM + scol * 8;
    const unsigned short* gB = B + (size_t)(n0 + srow) * K_DIM + scol * 8;

#define STAGE_A(NXT, i, ktn) \
    __builtin_amdgcn_global_load_lds( \
        (__attribute__((address_space(1))) void*)(gA + (size_t)((i) * 64) * K_DIM + (ktn) * BK), \
        (__attribute__((address_space(3))) void*)(&As[NXT][(i) * 4096 + wave * 512]), 16, 0, 0)
#define STAGE_B(NXT, i, ktn) \
    __builtin_amdgcn_global_load_lds( \
        (__attribute__((address_space(1))) void*)(gB + (size_t)((i) * 64) * K_DIM + (ktn) * BK), \
        (__attribute__((address_space(3))) void*)(&Bs[NXT][(i) * 4096 + wave * 512]), 16, 0, 0)

#define VMCNT(n) asm volatile("s_waitcnt vmcnt(" #n ")" ::: "memory")

// One phase: 12 ds_read_b128 (quadrant frags) + stage issue -> barrier -> lgkm(0) ->
// setprio-wrapped 16 MFMA -> counted vmcnt (if due) -> barrier.
#define PHASE(CUR, MI0, NJ0, WAIT, ...) do { \
    bf16x8 af[4][2], bfr[2][2]; \
    _Pragma("unroll") \
    for (int i = 0; i < 4; ++i) { \
      _Pragma("unroll") \
      for (int kk = 0; kk < 2; ++kk) \
        af[i][kk] = *(const bf16x8*)(&As[CUR][(wm + ((MI0) + i) * 16 + l16) * BK + ((kk * 4 + quad) ^ (l16 & 7)) * 8]); \
    } \
    _Pragma("unroll") \
    for (int j = 0; j < 2; ++j) { \
      _Pragma("unroll") \
      for (int kk = 0; kk < 2; ++kk) \
        bfr[j][kk] = *(const bf16x8*)(&Bs[CUR][(wn + ((NJ0) + j) * 16 + l16) * BK + ((kk * 4 + quad) ^ (l16 & 7)) * 8]); \
    } \
    __VA_ARGS__; \
    __builtin_amdgcn_s_barrier(); \
    asm volatile("s_waitcnt lgkmcnt(0)" ::: "memory"); \
    __builtin_amdgcn_s_setprio(1); \
    _Pragma("unroll") \
    for (int i = 0; i < 4; ++i) { \
      _Pragma("unroll") \
      for (int j = 0; j < 2; ++j) { \
        acc[(MI0) + i][(NJ0) + j] = __builtin_amdgcn_mfma_f32_16x16x32_bf16(af[i][0], bfr[j][0], acc[(MI0) + i][(NJ0) + j], 0, 0, 0); \
        acc[(MI0) + i][(NJ0) + j] = __builtin_amdgcn_mfma_f32_16x16x32_bf16(af[i][1], bfr[j][1], acc[(MI0) + i][(NJ0) + j], 0, 0, 0); \
      } \
    } \
    __builtin_amdgcn_s_setprio(0); \
    WAIT; \
    __builtin_amdgcn_s_barrier(); \
  } while (0)

#define TILE_FULL(CUR, NXT, KTN) do { \
    PHASE(CUR, 0, 0, (void)0, STAGE_B(NXT, 0, KTN); STAGE_B(NXT, 1, KTN); STAGE_B(NXT, 2, KTN)); \
    PHASE(CUR, 0, 2, VMCNT(6), STAGE_B(NXT, 3, KTN); STAGE_A(NXT, 0, KTN); STAGE_A(NXT, 2, KTN)); \
    PHASE(CUR, 4, 0, (void)0, STAGE_A(NXT, 1, KTN); STAGE_A(NXT, 3, KTN)); \
    PHASE(CUR, 4, 2, VMCNT(2), (void)0); \
  } while (0)

#define TILE_LAST(CUR) do { \
    PHASE(CUR, 0, 0, (void)0, (void)0); \
    PHASE(CUR, 0, 2, VMCNT(0), (void)0); \
    PHASE(CUR, 4, 0, (void)0, (void)0); \
    PHASE(CUR, 4, 2, (void)0, (void)0); \
  } while (0)

    // Prologue: stage tile 0 into buf0; last two issued = A1,A3 (matches loop invariant
    // "entering a tile, exactly its A1,A3 loads may still be in flight").
    STAGE_B(0, 0, 0); STAGE_B(0, 1, 0); STAGE_B(0, 2, 0); STAGE_B(0, 3, 0);
    STAGE_A(0, 0, 0); STAGE_A(0, 2, 0); STAGE_A(0, 1, 0); STAGE_A(0, 3, 0);
    VMCNT(2);
    __builtin_amdgcn_s_barrier();

    for (int kt = 0; kt < NT - 2; kt += 2) {
        TILE_FULL(0, 1, kt + 1);   // compute tile kt   (buf0), stage tile kt+1 -> buf1
        TILE_FULL(1, 0, kt + 2);   // compute tile kt+1 (buf1), stage tile kt+2 -> buf0
    }
    TILE_FULL(0, 1, NT - 1);       // compute tile 30 (buf0), stage tile 31 -> buf1
    TILE_LAST(1);                  // compute tile 31 (buf1), no staging

    // C/D layout: row = quad*4 + reg, col = lane&15
#pragma unroll
    for (int i = 0; i < 8; ++i) {
        const int row = m0 + wm + i * 16 + quad * 4;
#pragma unroll
        for (int j = 0; j < 4; ++j) {
            const int col = n0 + wn + j * 16 + l16;
            float* cp = C + (size_t)row * N_DIM + col;
#pragma unroll
            for (int r = 0; r < 4; ++r)
                cp[(size_t)r * N_DIM] = acc[i][j][r];
        }
    }
}

extern "C" void kernel_launch(void* const* d_in, const int* in_sizes, int n_in,
                              void* d_out, int out_size, void* d_ws, size_t ws_size,
                              hipStream_t stream) {
    const float* x      = (const float*)d_in[0];
    const float* wfp8   = (const float*)d_in[1];
    const float* wscale = (const float*)d_in[2];
    float* out = (float*)d_out;

    unsigned short* xdq = (unsigned short*)d_ws;                    // M*K bf16
    unsigned short* wdq = xdq + (size_t)M_DIM * K_DIM;              // N*K bf16

    quant_all_kernel<<<XGRID + WGRID, 256, 0, stream>>>(x, xdq, wfp8, wscale, wdq);
    gemm_bt_kernel<<<dim3(M_DIM / BM, N_DIM / BN), 512, 0, stream>>>(xdq, wdq, out);
}

// Round 2
// 371.082 us; speedup vs baseline: 1.0259x; 1.0259x over previous
//
#include <hip/hip_runtime.h>

#define M_DIM 16384
#define N_DIM 2048
#define K_DIM 2048
#define KB    (K_DIM / 128)

// GEMM geometry: 256x256 tile, BK=64, 8 waves (2M x 4N), double-buffered 128 KiB LDS
#define BM 256
#define BN 256
#define BK 64
#define NT (K_DIM / BK)   // 32 K-tiles

// quant grid partition: 256 threads x 8 floats per block
#define XGRID (M_DIM * K_DIM / 2048)   // 16384
#define WGRID (N_DIM * K_DIM / 2048)   // 2048

typedef __bf16 bf16x8 __attribute__((ext_vector_type(8)));
typedef float  f32x4  __attribute__((ext_vector_type(4)));

__device__ __forceinline__ unsigned short f32_to_bf16_rne(float f) {
    unsigned int u = __float_as_uint(f);
    u += 0x7FFFu + ((u >> 16) & 1u);
    return (unsigned short)(u >> 16);
}

// ---- Fused pass: activation quant+dequant (blocks [0,XGRID)) and weight dequant ----
__global__ __launch_bounds__(256) void quant_all_kernel(const float* __restrict__ x,
                                                        unsigned short* __restrict__ xdq,
                                                        const float* __restrict__ w,
                                                        const float* __restrict__ wscale,
                                                        unsigned short* __restrict__ wdq) {
    const int tid = threadIdx.x;
    if (blockIdx.x < XGRID) {
        // 16 consecutive lanes cover one 128-elem K-block (8 floats each)
        const size_t base = ((size_t)blockIdx.x * 256 + tid) * 8;
        const float4 va = *(const float4*)(x + base);
        const float4 vb = *(const float4*)(x + base + 4);
        float amax = fmaxf(
            fmaxf(fmaxf(fabsf(va.x), fabsf(va.y)), fmaxf(fabsf(va.z), fabsf(va.w))),
            fmaxf(fmaxf(fabsf(vb.x), fabsf(vb.y)), fmaxf(fabsf(vb.z), fabsf(vb.w))));
#pragma unroll
        for (int m = 8; m >= 1; m >>= 1)
            amax = fmaxf(amax, __shfl_xor(amax, m, 64));
        float s = amax / 448.0f;                  // true f32 div (matches reference)
        if (s == 0.0f) s = 1.0f;
        const int p01 = __builtin_amdgcn_cvt_pk_fp8_f32(va.x / s, va.y / s, 0, false);
        const int p23 = __builtin_amdgcn_cvt_pk_fp8_f32(va.z / s, va.w / s, 0, false);
        const int p45 = __builtin_amdgcn_cvt_pk_fp8_f32(vb.x / s, vb.y / s, 0, false);
        const int p67 = __builtin_amdgcn_cvt_pk_fp8_f32(vb.z / s, vb.w / s, 0, false);
        uint4 out;
        out.x = (unsigned int)f32_to_bf16_rne(__builtin_amdgcn_cvt_f32_fp8(p01, 0) * s)
              | ((unsigned int)f32_to_bf16_rne(__builtin_amdgcn_cvt_f32_fp8(p01, 1) * s) << 16);
        out.y = (unsigned int)f32_to_bf16_rne(__builtin_amdgcn_cvt_f32_fp8(p23, 0) * s)
              | ((unsigned int)f32_to_bf16_rne(__builtin_amdgcn_cvt_f32_fp8(p23, 1) * s) << 16);
        out.z = (unsigned int)f32_to_bf16_rne(__builtin_amdgcn_cvt_f32_fp8(p45, 0) * s)
              | ((unsigned int)f32_to_bf16_rne(__builtin_amdgcn_cvt_f32_fp8(p45, 1) * s) << 16);
        out.w = (unsigned int)f32_to_bf16_rne(__builtin_amdgcn_cvt_f32_fp8(p67, 0) * s)
              | ((unsigned int)f32_to_bf16_rne(__builtin_amdgcn_cvt_f32_fp8(p67, 1) * s) << 16);
        *(uint4*)(xdq + base) = out;
    } else {
        const size_t e = ((size_t)(blockIdx.x - XGRID) * 256 + tid) * 8;
        const float4 va = *(const float4*)(w + e);
        const float4 vb = *(const float4*)(w + e + 4);
        const int n = (int)(e >> 11);
        const int k = (int)(e & 2047);
        const float s = wscale[(n >> 7) * KB + (k >> 7)];   // k..k+7 same 128-block
        uint4 out;
        out.x = (unsigned int)f32_to_bf16_rne(va.x * s) | ((unsigned int)f32_to_bf16_rne(va.y * s) << 16);
        out.y = (unsigned int)f32_to_bf16_rne(va.z * s) | ((unsigned int)f32_to_bf16_rne(va.w * s) << 16);
        out.z = (unsigned int)f32_to_bf16_rne(vb.x * s) | ((unsigned int)f32_to_bf16_rne(vb.y * s) << 16);
        out.w = (unsigned int)f32_to_bf16_rne(vb.z * s) | ((unsigned int)f32_to_bf16_rne(vb.w * s) << 16);
        *(uint4*)(wdq + e) = out;
    }
}

// ---- GEMM: C = A @ B^T, bf16 in, f32 out. 256x256 tile, kk-split 2-phase schedule ----
//
// LDS: As/Bs[buf][kh][256 rows][32 cols] — each K-tile split into two kk-panels of 4
// 16B-chunks. One stage unit = 128 rows x 1 panel = one global_load_lds per thread.
// Phase = {stage 4 units; read af[8]+bfr[4] (12 ds_read_b128); 32 MFMA; vmcnt(N); barrier}.
// Single barrier per phase: per-wave lgkm waits (compiler) guarantee phase-p reads done
// before the wave's barrier arrival, so stage-issues of phase p+1 can't clobber live data;
// per-wave vmcnt before the barrier guarantees staged data visible to all after it.
// Ledger (steady state, 4 loads/phase, waits NEVER drain):
//   P0(t): stage k1(t+1)->buf[t+1]  |  P1(t): stage k0(t+2)->buf[t]
//   issue seq: ... k1(t)@P0(t-1), k0(t+1)@P1(t-1), k1(t+1)@P0(t), k0(t+2)@P1(t) ...
//   every phase ends vmcnt(8): retires the unit needed next phase, leaves 8 in flight,
//   ~2 full phases (~2000 cyc) of latency slack per load.
// Swizzle: physical chunk p holds logical chunk p ^ ((row>>1)&3) (staging pre-swizzles the
// per-lane global source; reads XOR) — 2-lanes-per-bank within 16-lane groups = free.
__global__ __launch_bounds__(512, 2) void gemm_bt_kernel(const unsigned short* __restrict__ A,
                                                         const unsigned short* __restrict__ B,
                                                         float* __restrict__ C) {
    __shared__ __align__(16) unsigned short As[2][2][256][32];   // 64 KiB
    __shared__ __align__(16) unsigned short Bs[2][2][256][32];   // 64 KiB

    const int tid  = threadIdx.x;
    const int lane = tid & 63;
    const int wave = tid >> 6;
    const int wm   = (wave >> 2) * 128;   // 2 waves along M
    const int wn   = (wave & 3) * 64;     // 4 waves along N
    const int quad = lane >> 4;
    const int l16  = lane & 15;
    const int pc   = quad ^ ((l16 >> 1) & 3);   // physical chunk within a kk-panel

    // grid: x carries M so XCD round-robin partitions A-slabs
    const int m0 = blockIdx.x * BM;
    const int n0 = blockIdx.y * BN;

    f32x4 acc[8][4] = {};

    // Staging: one unit = 512 lanes x 16B = 128 rows x 4 chunks, lane-linear in LDS.
    // Lane: row = tid>>2, physical chunk tid&3; source chunk pre-swizzled.
    const int srow = tid >> 2;                       // 0..127
    const int sc   = (tid & 3) ^ ((tid >> 3) & 3);   // (row>>1)&3 == (tid>>3)&3
    const unsigned short* gA = A + (size_t)(m0 + srow) * K_DIM + sc * 8;
    const unsigned short* gB = B + (size_t)(n0 + srow) * K_DIM + sc * 8;

#define GLD(SRC, DST) __builtin_amdgcn_global_load_lds( \
    (__attribute__((address_space(1))) void*)(SRC), \
    (__attribute__((address_space(3))) void*)(DST), 16, 0, 0)

#define STAGE4(BUF, KH, KT) do { \
    GLD(gA + (size_t)(KT) * 64 + (KH) * 32,                       &As[BUF][KH][wave * 16][0]); \
    GLD(gA + (size_t)128 * K_DIM + (size_t)(KT) * 64 + (KH) * 32, &As[BUF][KH][128 + wave * 16][0]); \
    GLD(gB + (size_t)(KT) * 64 + (KH) * 32,                       &Bs[BUF][KH][wave * 16][0]); \
    GLD(gB + (size_t)128 * K_DIM + (size_t)(KT) * 64 + (KH) * 32, &Bs[BUF][KH][128 + wave * 16][0]); \
  } while (0)

#define VMCNT(n) asm volatile("s_waitcnt vmcnt(" #n ")" ::: "memory")
#define BAR() __builtin_amdgcn_s_barrier()

#define PHASE(BUF, KK, WAIT, STAGES) do { \
    STAGES; \
    bf16x8 af[8], bfr[4]; \
    _Pragma("unroll") \
    for (int i = 0; i < 8; ++i) \
      af[i] = *(const bf16x8*)(&As[BUF][KK][wm + i * 16 + l16][pc * 8]); \
    _Pragma("unroll") \
    for (int j = 0; j < 4; ++j) \
      bfr[j] = *(const bf16x8*)(&Bs[BUF][KK][wn + j * 16 + l16][pc * 8]); \
    __builtin_amdgcn_s_setprio(1); \
    _Pragma("unroll") \
    for (int i = 0; i < 8; ++i) { \
      _Pragma("unroll") \
      for (int j = 0; j < 4; ++j) \
        acc[i][j] = __builtin_amdgcn_mfma_f32_16x16x32_bf16(af[i], bfr[j], acc[i][j], 0, 0, 0); \
    } \
    __builtin_amdgcn_s_setprio(0); \
    WAIT; \
    BAR(); \
  } while (0)

    // Prologue: k0(0), k1(0) -> buf0; k0(1) -> buf1. Retire k0(0) only (8 stay in flight).
    STAGE4(0, 0, 0);
    STAGE4(0, 1, 0);
    STAGE4(1, 0, 1);
    VMCNT(8);
    BAR();

#pragma unroll 1
    for (int t = 0; t < NT - 2; t += 2) {
        PHASE(0, 0, VMCNT(8), STAGE4(1, 1, t + 1));   // tile t   kk=0; stage k1(t+1)
        PHASE(0, 1, VMCNT(8), STAGE4(0, 0, t + 2));   // tile t   kk=1; stage k0(t+2)
        PHASE(1, 0, VMCNT(8), STAGE4(0, 1, t + 2));   // tile t+1 kk=0; stage k1(t+2)
        PHASE(1, 1, VMCNT(8), STAGE4(1, 0, t + 3));   // tile t+1 kk=1; stage k0(t+3)
    }
    // Epilogue tiles NT-2 (buf0), NT-1 (buf1)
    PHASE(0, 0, VMCNT(8), STAGE4(1, 1, NT - 1));
    PHASE(0, 1, VMCNT(4), (void)0);
    PHASE(1, 0, VMCNT(0), (void)0);
    PHASE(1, 1, (void)0, (void)0);

    // C/D layout: row = quad*4 + reg, col = lane&15
#pragma unroll
    for (int i = 0; i < 8; ++i) {
        const int row = m0 + wm + i * 16 + quad * 4;
#pragma unroll
        for (int j = 0; j < 4; ++j) {
            const int col = n0 + wn + j * 16 + l16;
            float* cp = C + (size_t)row * N_DIM + col;
#pragma unroll
            for (int r = 0; r < 4; ++r)
                cp[(size_t)r * N_DIM] = acc[i][j][r];
        }
    }
}

extern "C" void kernel_launch(void* const* d_in, const int* in_sizes, int n_in,
                              void* d_out, int out_size, void* d_ws, size_t ws_size,
                              hipStream_t stream) {
    const float* x      = (const float*)d_in[0];
    const float* wfp8   = (const float*)d_in[1];
    const float* wscale = (const float*)d_in[2];
    float* out = (float*)d_out;

    unsigned short* xdq = (unsigned short*)d_ws;                    // M*K bf16
    unsigned short* wdq = xdq + (size_t)M_DIM * K_DIM;              // N*K bf16

    quant_all_kernel<<<XGRID + WGRID, 256, 0, stream>>>(x, xdq, wfp8, wscale, wdq);
    gemm_bt_kernel<<<dim3(M_DIM / BM, N_DIM / BN), 512, 0, stream>>>(xdq, wdq, out);
}

// Round 3
// 363.141 us; speedup vs baseline: 1.0484x; 1.0219x over previous
//
#include <hip/hip_runtime.h>

#define M_DIM 16384
#define N_DIM 2048
#define K_DIM 2048
#define KB    (K_DIM / 128)

// GEMM geometry: 256x256 tile, BK=64, 8 waves (2M x 4N), double-buffered 128 KiB LDS
#define BM 256
#define BN 256
#define BK 64
#define NT (K_DIM / BK)   // 32 K-tiles

// quant grid partition: 256 threads x 8 floats per block
#define XGRID (M_DIM * K_DIM / 2048)   // 16384
#define WGRID (N_DIM * K_DIM / 2048)   // 2048

typedef __bf16 bf16x8 __attribute__((ext_vector_type(8)));
typedef float  f32x4  __attribute__((ext_vector_type(4)));

__device__ __forceinline__ unsigned short f32_to_bf16_rne(float f) {
    unsigned int u = __float_as_uint(f);
    u += 0x7FFFu + ((u >> 16) & 1u);
    return (unsigned short)(u >> 16);
}

// ---- Fused pass: activation quant+dequant (blocks [0,XGRID)) and weight dequant ----
__global__ __launch_bounds__(256) void quant_all_kernel(const float* __restrict__ x,
                                                        unsigned short* __restrict__ xdq,
                                                        const float* __restrict__ w,
                                                        const float* __restrict__ wscale,
                                                        unsigned short* __restrict__ wdq) {
    const int tid = threadIdx.x;
    if (blockIdx.x < XGRID) {
        // 16 consecutive lanes cover one 128-elem K-block (8 floats each)
        const size_t base = ((size_t)blockIdx.x * 256 + tid) * 8;
        const float4 va = *(const float4*)(x + base);
        const float4 vb = *(const float4*)(x + base + 4);
        float amax = fmaxf(
            fmaxf(fmaxf(fabsf(va.x), fabsf(va.y)), fmaxf(fabsf(va.z), fabsf(va.w))),
            fmaxf(fmaxf(fabsf(vb.x), fabsf(vb.y)), fmaxf(fabsf(vb.z), fabsf(vb.w))));
#pragma unroll
        for (int m = 8; m >= 1; m >>= 1)
            amax = fmaxf(amax, __shfl_xor(amax, m, 64));
        float s = amax / 448.0f;                  // true f32 div (matches reference)
        if (s == 0.0f) s = 1.0f;
        const int p01 = __builtin_amdgcn_cvt_pk_fp8_f32(va.x / s, va.y / s, 0, false);
        const int p23 = __builtin_amdgcn_cvt_pk_fp8_f32(va.z / s, va.w / s, 0, false);
        const int p45 = __builtin_amdgcn_cvt_pk_fp8_f32(vb.x / s, vb.y / s, 0, false);
        const int p67 = __builtin_amdgcn_cvt_pk_fp8_f32(vb.z / s, vb.w / s, 0, false);
        uint4 out;
        out.x = (unsigned int)f32_to_bf16_rne(__builtin_amdgcn_cvt_f32_fp8(p01, 0) * s)
              | ((unsigned int)f32_to_bf16_rne(__builtin_amdgcn_cvt_f32_fp8(p01, 1) * s) << 16);
        out.y = (unsigned int)f32_to_bf16_rne(__builtin_amdgcn_cvt_f32_fp8(p23, 0) * s)
              | ((unsigned int)f32_to_bf16_rne(__builtin_amdgcn_cvt_f32_fp8(p23, 1) * s) << 16);
        out.z = (unsigned int)f32_to_bf16_rne(__builtin_amdgcn_cvt_f32_fp8(p45, 0) * s)
              | ((unsigned int)f32_to_bf16_rne(__builtin_amdgcn_cvt_f32_fp8(p45, 1) * s) << 16);
        out.w = (unsigned int)f32_to_bf16_rne(__builtin_amdgcn_cvt_f32_fp8(p67, 0) * s)
              | ((unsigned int)f32_to_bf16_rne(__builtin_amdgcn_cvt_f32_fp8(p67, 1) * s) << 16);
        *(uint4*)(xdq + base) = out;
    } else {
        const size_t e = ((size_t)(blockIdx.x - XGRID) * 256 + tid) * 8;
        const float4 va = *(const float4*)(w + e);
        const float4 vb = *(const float4*)(w + e + 4);
        const int n = (int)(e >> 11);
        const int k = (int)(e & 2047);
        const float s = wscale[(n >> 7) * KB + (k >> 7)];   // k..k+7 same 128-block
        uint4 out;
        out.x = (unsigned int)f32_to_bf16_rne(va.x * s) | ((unsigned int)f32_to_bf16_rne(va.y * s) << 16);
        out.y = (unsigned int)f32_to_bf16_rne(va.z * s) | ((unsigned int)f32_to_bf16_rne(va.w * s) << 16);
        out.z = (unsigned int)f32_to_bf16_rne(vb.x * s) | ((unsigned int)f32_to_bf16_rne(vb.y * s) << 16);
        out.w = (unsigned int)f32_to_bf16_rne(vb.z * s) | ((unsigned int)f32_to_bf16_rne(vb.w * s) << 16);
        *(uint4*)(wdq + e) = out;
    }
}

// ---- GEMM: C = A @ B^T, bf16 in, f32 out. 256x256 tile, 8-phase dual-barrier schedule ----
//
// LDS: As/Bs[buf][kk][256 rows][32 cols] — K-tile split into two kk-panels of 4 16B-chunks.
// One gload unit = 512 lanes x 16B = 128 rows x 1 panel; A-panel = 2 units, B-panel = 2.
//
// 4 phases per K-tile (16 MFMA each), m201 dual-barrier form:
//   [reads for this phase; 2 stage gloads]  BAR(open)  [setprio1; 16 MFMA; setprio0]
//   [counted VMCNT if due]  BAR(close)
// Phase p+1's reads issue between close(p) and open(p+1): LDS drains while other waves
// finish p's MFMA cluster. Phases alternate 10-read (af[8]+b01) / 2-read (b23, af held).
//
// Staging ledger (2 units/phase, vmcnt NEVER drains in steady state):
//   tile t: ph0: A-kk1(t+1)->buf^1   ph1: B-kk1(t+1)->buf^1
//           ph2: A-kk0(t+2)->buf     ph3: B-kk0(t+2)->buf
//   (buf.kk0 was read only in ph0/ph1 — safe to overwrite from ph2 on.)
//   Waits: end-ph1 vmcnt(8) retires kk1(t) [needed in ph2; issued t-1 ph0/ph1;
//   8 younger in flight]; end-ph3 vmcnt(8) retires kk0(t+1) [needed t+1 ph0; issued
//   t-1 ph2/ph3; 8 younger]. Each unit retires ~6 phases after issue (~5000 cyc slack).
// Swizzle: physical chunk = logical ^ ((row>>1)&3) (staging pre-swizzles the per-lane
// GLOBAL source; reads XOR) — measured SQ_LDS_BANK_CONFLICT = 0 with this pattern.
__global__ __launch_bounds__(512, 2) void gemm_bt_kernel(const unsigned short* __restrict__ A,
                                                         const unsigned short* __restrict__ B,
                                                         float* __restrict__ C) {
    __shared__ __align__(16) unsigned short As[2][2][256][32];   // 64 KiB
    __shared__ __align__(16) unsigned short Bs[2][2][256][32];   // 64 KiB

    const int tid  = threadIdx.x;
    const int lane = tid & 63;
    const int wave = tid >> 6;
    const int wm   = (wave >> 2) * 128;   // 2 waves along M
    const int wn   = (wave & 3) * 64;     // 4 waves along N
    const int quad = lane >> 4;
    const int l16  = lane & 15;
    const int pc   = quad ^ ((l16 >> 1) & 3);   // physical chunk within a kk-panel

    // grid: x carries M so XCD round-robin partitions A-slabs
    const int m0 = blockIdx.x * BM;
    const int n0 = blockIdx.y * BN;

    f32x4 acc[8][4] = {};

    // Staging: lane row = tid>>2 (0..127), physical chunk tid&3; source chunk pre-swizzled.
    const int srow = tid >> 2;
    const int sc   = (tid & 3) ^ ((tid >> 3) & 3);   // (row>>1)&3 == (tid>>3)&3
    const unsigned short* gA = A + (size_t)(m0 + srow) * K_DIM + sc * 8;
    const unsigned short* gB = B + (size_t)(n0 + srow) * K_DIM + sc * 8;

#define GLD(SRC, DST) __builtin_amdgcn_global_load_lds( \
    (__attribute__((address_space(1))) void*)(SRC), \
    (__attribute__((address_space(3))) void*)(DST), 16, 0, 0)

#define STG_A(DB, KH, KT) do { \
    GLD(gA + (size_t)(KT) * 64 + (KH) * 32,                       &As[DB][KH][wave * 16][0]); \
    GLD(gA + (size_t)128 * K_DIM + (size_t)(KT) * 64 + (KH) * 32, &As[DB][KH][128 + wave * 16][0]); \
  } while (0)
#define STG_B(DB, KH, KT) do { \
    GLD(gB + (size_t)(KT) * 64 + (KH) * 32,                       &Bs[DB][KH][wave * 16][0]); \
    GLD(gB + (size_t)128 * K_DIM + (size_t)(KT) * 64 + (KH) * 32, &Bs[DB][KH][128 + wave * 16][0]); \
  } while (0)

#define VMCNT(n) asm volatile("s_waitcnt vmcnt(" #n ")" ::: "memory")
#define BAR() __builtin_amdgcn_s_barrier()

#define LDA(BUF, KK, i) (*(const bf16x8*)(&As[BUF][KK][wm + (i) * 16 + l16][pc * 8]))
#define LDB(BUF, KK, j) (*(const bf16x8*)(&Bs[BUF][KK][wn + (j) * 16 + l16][pc * 8]))

#define MM8x2(J0, B0, B1) do { \
    __builtin_amdgcn_s_setprio(1); \
    _Pragma("unroll") \
    for (int i = 0; i < 8; ++i) { \
      acc[i][J0]     = __builtin_amdgcn_mfma_f32_16x16x32_bf16(af[i], B0, acc[i][J0],     0, 0, 0); \
      acc[i][(J0)+1] = __builtin_amdgcn_mfma_f32_16x16x32_bf16(af[i], B1, acc[i][(J0)+1], 0, 0, 0); \
    } \
    __builtin_amdgcn_s_setprio(0); \
  } while (0)

// One K-tile = 4 phases. S0..S3 = staging issued per phase; W1/W3 = counted waits.
#define TILE(BUF, S0, S1, S2, S3, W1, W3) do { \
    bf16x8 af[8], b0, b1; \
    _Pragma("unroll") \
    for (int i = 0; i < 8; ++i) af[i] = LDA(BUF, 0, i); \
    b0 = LDB(BUF, 0, 0); b1 = LDB(BUF, 0, 1); \
    S0; BAR(); MM8x2(0, b0, b1); BAR(); \
    b0 = LDB(BUF, 0, 2); b1 = LDB(BUF, 0, 3); \
    S1; BAR(); MM8x2(2, b0, b1); W1; BAR(); \
    _Pragma("unroll") \
    for (int i = 0; i < 8; ++i) af[i] = LDA(BUF, 1, i); \
    b0 = LDB(BUF, 1, 0); b1 = LDB(BUF, 1, 1); \
    S2; BAR(); MM8x2(0, b0, b1); BAR(); \
    b0 = LDB(BUF, 1, 2); b1 = LDB(BUF, 1, 3); \
    S3; BAR(); MM8x2(2, b0, b1); W3; BAR(); \
  } while (0)

    // Prologue: kk0(0), kk1(0) -> buf0; kk0(1) -> buf1 (12 gloads). vmcnt(8) retires
    // kk0(0) only; in-flight order {kk1(0) x4, kk0(1) x4} matches the loop invariant.
    STG_A(0, 0, 0); STG_B(0, 0, 0);
    STG_A(0, 1, 0); STG_B(0, 1, 0);
    STG_A(1, 0, 1); STG_B(1, 0, 1);
    VMCNT(8);
    BAR();

#pragma unroll 1
    for (int t = 0; t < NT - 2; t += 2) {
        TILE(0, STG_A(1, 1, t + 1), STG_B(1, 1, t + 1),
                STG_A(0, 0, t + 2), STG_B(0, 0, t + 2), VMCNT(8), VMCNT(8));
        TILE(1, STG_A(0, 1, t + 2), STG_B(0, 1, t + 2),
                STG_A(1, 0, t + 3), STG_B(1, 0, t + 3), VMCNT(8), VMCNT(8));
    }
    // Tile 30 (buf0): stage only kk1(31); tile 31 (buf1): drain.
    TILE(0, STG_A(1, 1, NT - 1), STG_B(1, 1, NT - 1), (void)0, (void)0, VMCNT(8), VMCNT(4));
    TILE(1, (void)0, (void)0, (void)0, (void)0, VMCNT(0), (void)0);

    // C/D layout: row = quad*4 + reg, col = lane&15
#pragma unroll
    for (int i = 0; i < 8; ++i) {
        const int row = m0 + wm + i * 16 + quad * 4;
#pragma unroll
        for (int j = 0; j < 4; ++j) {
            const int col = n0 + wn + j * 16 + l16;
            float* cp = C + (size_t)row * N_DIM + col;
#pragma unroll
            for (int r = 0; r < 4; ++r)
                cp[(size_t)r * N_DIM] = acc[i][j][r];
        }
    }
}

extern "C" void kernel_launch(void* const* d_in, const int* in_sizes, int n_in,
                              void* d_out, int out_size, void* d_ws, size_t ws_size,
                              hipStream_t stream) {
    const float* x      = (const float*)d_in[0];
    const float* wfp8   = (const float*)d_in[1];
    const float* wscale = (const float*)d_in[2];
    float* out = (float*)d_out;

    unsigned short* xdq = (unsigned short*)d_ws;                    // M*K bf16
    unsigned short* wdq = xdq + (size_t)M_DIM * K_DIM;              // N*K bf16

    quant_all_kernel<<<XGRID + WGRID, 256, 0, stream>>>(x, xdq, wfp8, wscale, wdq);
    gemm_bt_kernel<<<dim3(M_DIM / BM, N_DIM / BN), 512, 0, stream>>>(xdq, wdq, out);
}

// Round 4
// 361.028 us; speedup vs baseline: 1.0545x; 1.0059x over previous
//
#include <hip/hip_runtime.h>

#define M_DIM 16384
#define N_DIM 2048
#define K_DIM 2048
#define KB    (K_DIM / 128)

// GEMM geometry: 256x256 tile, BK=64, 8 waves (2M x 4N), double-buffered 128 KiB LDS
#define BM 256
#define BN 256
#define BK 64
#define NT (K_DIM / BK)   // 32 K-tiles

// quant grid partition: 256 threads x 8 floats per block
#define XGRID (M_DIM * K_DIM / 2048)   // 16384
#define WGRID (N_DIM * K_DIM / 2048)   // 2048

typedef __bf16 bf16x8 __attribute__((ext_vector_type(8)));
typedef float  f32x16 __attribute__((ext_vector_type(16)));

__device__ __forceinline__ unsigned short f32_to_bf16_rne(float f) {
    unsigned int u = __float_as_uint(f);
    u += 0x7FFFu + ((u >> 16) & 1u);
    return (unsigned short)(u >> 16);
}

// ---- Fused pass: activation quant+dequant (blocks [0,XGRID)) and weight dequant ----
__global__ __launch_bounds__(256) void quant_all_kernel(const float* __restrict__ x,
                                                        unsigned short* __restrict__ xdq,
                                                        const float* __restrict__ w,
                                                        const float* __restrict__ wscale,
                                                        unsigned short* __restrict__ wdq) {
    const int tid = threadIdx.x;
    if (blockIdx.x < XGRID) {
        // 16 consecutive lanes cover one 128-elem K-block (8 floats each)
        const size_t base = ((size_t)blockIdx.x * 256 + tid) * 8;
        const float4 va = *(const float4*)(x + base);
        const float4 vb = *(const float4*)(x + base + 4);
        float amax = fmaxf(
            fmaxf(fmaxf(fabsf(va.x), fabsf(va.y)), fmaxf(fabsf(va.z), fabsf(va.w))),
            fmaxf(fmaxf(fabsf(vb.x), fabsf(vb.y)), fmaxf(fabsf(vb.z), fabsf(vb.w))));
#pragma unroll
        for (int m = 8; m >= 1; m >>= 1)
            amax = fmaxf(amax, __shfl_xor(amax, m, 64));
        float s = amax / 448.0f;                  // true f32 div (matches reference)
        if (s == 0.0f) s = 1.0f;
        const int p01 = __builtin_amdgcn_cvt_pk_fp8_f32(va.x / s, va.y / s, 0, false);
        const int p23 = __builtin_amdgcn_cvt_pk_fp8_f32(va.z / s, va.w / s, 0, false);
        const int p45 = __builtin_amdgcn_cvt_pk_fp8_f32(vb.x / s, vb.y / s, 0, false);
        const int p67 = __builtin_amdgcn_cvt_pk_fp8_f32(vb.z / s, vb.w / s, 0, false);
        uint4 out;
        out.x = (unsigned int)f32_to_bf16_rne(__builtin_amdgcn_cvt_f32_fp8(p01, 0) * s)
              | ((unsigned int)f32_to_bf16_rne(__builtin_amdgcn_cvt_f32_fp8(p01, 1) * s) << 16);
        out.y = (unsigned int)f32_to_bf16_rne(__builtin_amdgcn_cvt_f32_fp8(p23, 0) * s)
              | ((unsigned int)f32_to_bf16_rne(__builtin_amdgcn_cvt_f32_fp8(p23, 1) * s) << 16);
        out.z = (unsigned int)f32_to_bf16_rne(__builtin_amdgcn_cvt_f32_fp8(p45, 0) * s)
              | ((unsigned int)f32_to_bf16_rne(__builtin_amdgcn_cvt_f32_fp8(p45, 1) * s) << 16);
        out.w = (unsigned int)f32_to_bf16_rne(__builtin_amdgcn_cvt_f32_fp8(p67, 0) * s)
              | ((unsigned int)f32_to_bf16_rne(__builtin_amdgcn_cvt_f32_fp8(p67, 1) * s) << 16);
        *(uint4*)(xdq + base) = out;
    } else {
        const size_t e = ((size_t)(blockIdx.x - XGRID) * 256 + tid) * 8;
        const float4 va = *(const float4*)(w + e);
        const float4 vb = *(const float4*)(w + e + 4);
        const int n = (int)(e >> 11);
        const int k = (int)(e & 2047);
        const float s = wscale[(n >> 7) * KB + (k >> 7)];   // k..k+7 same 128-block
        uint4 out;
        out.x = (unsigned int)f32_to_bf16_rne(va.x * s) | ((unsigned int)f32_to_bf16_rne(va.y * s) << 16);
        out.y = (unsigned int)f32_to_bf16_rne(va.z * s) | ((unsigned int)f32_to_bf16_rne(va.w * s) << 16);
        out.z = (unsigned int)f32_to_bf16_rne(vb.x * s) | ((unsigned int)f32_to_bf16_rne(vb.y * s) << 16);
        out.w = (unsigned int)f32_to_bf16_rne(vb.z * s) | ((unsigned int)f32_to_bf16_rne(vb.w * s) << 16);
        *(uint4*)(wdq + e) = out;
    }
}

// ---- GEMM: C = A @ B^T, bf16 in, f32 out. 256x256 tile, 32x32x16 MFMA,
//      register-prefetch pipeline, 2 barriers per K-tile ----
//
// LDS: As/Bs[buf][256 rows][64 K] row-major (128 B rows, 8x 16B chunks), physical
// chunk = logical ^ (row&7) (staging pre-swizzles the per-lane GLOBAL source chunk;
// global_load_lds dest stays lane-linear; frag reads XOR).
//
// Per K-tile: 4 kk-steps (K=16 each). Step s: issue 6 ds_read_b128 for step s+1 into
// the alternate frag set -> issue staging gloads -> 8 MFMA on current set. Each wave's
// MFMA cluster shadows its own LDS drain (intra-wave overlap, barrier-independent).
// Barriers (2/tile):  end-kk2: vmcnt(0)+bar  — tile t+1 (staged kk0/kk1, ~1100 cyc
// slack, ~90% L2-hit) retired & visible before kk3 prefetches its kk0.
//                     end-kk3: bar — all waves' reads of buf[t-1&1] long done; tile
// t+1 may overwrite it at its kk0. vmcnt never waits on a just-issued load.
//
// 32x32x16 layouts: A/B lane l -> row/col l&31, k = 8*(l>>5)+j.
// C/D: col = lane&31, row = (reg&3) + 8*(reg>>2) + 4*(lane>>5)  [m74/m101 verified].
__global__ __launch_bounds__(512, 2) void gemm_bt_kernel(const unsigned short* __restrict__ A,
                                                         const unsigned short* __restrict__ B,
                                                         float* __restrict__ C) {
    __shared__ __align__(16) unsigned short As[2][256][64];   // 64 KiB
    __shared__ __align__(16) unsigned short Bs[2][256][64];   // 64 KiB

    const int tid  = threadIdx.x;
    const int lane = tid & 63;
    const int wave = tid >> 6;
    const int wm   = (wave >> 2) * 128;   // 2 waves along M
    const int wn   = (wave & 3) * 64;     // 4 waves along N
    const int l32  = lane & 31;
    const int hi   = lane >> 5;
    const int swz  = l32 & 7;             // (row&7) for all frag rows (wm,wn mult of 32)

    // grid: x carries M so XCD round-robin partitions A-slabs
    const int m0 = blockIdx.x * BM;
    const int n0 = blockIdx.y * BN;

    f32x16 acc[4][2] = {};

    // Staging: unit = 512 lanes x 16B = 64 rows x 8 chunks (full BK width).
    // Lane: row = tid>>3, physical chunk = tid&7; source chunk pre-swizzled.
    const int srow = tid >> 3;                    // 0..63
    const int sc   = (tid & 7) ^ (srow & 7);
    const unsigned short* gA = A + (size_t)(m0 + srow) * K_DIM + sc * 8;
    const unsigned short* gB = B + (size_t)(n0 + srow) * K_DIM + sc * 8;

#define GLD(SRC, DST) __builtin_amdgcn_global_load_lds( \
    (__attribute__((address_space(1))) void*)(SRC), \
    (__attribute__((address_space(3))) void*)(DST), 16, 0, 0)

#define STG_A4(DB, KT) do { \
    GLD(gA + (size_t)(KT) * 64,                        &As[DB][      wave * 8][0]); \
    GLD(gA + (size_t) 64 * K_DIM + (size_t)(KT) * 64,  &As[DB][ 64 + wave * 8][0]); \
    GLD(gA + (size_t)128 * K_DIM + (size_t)(KT) * 64,  &As[DB][128 + wave * 8][0]); \
    GLD(gA + (size_t)192 * K_DIM + (size_t)(KT) * 64,  &As[DB][192 + wave * 8][0]); \
  } while (0)
#define STG_B4(DB, KT) do { \
    GLD(gB + (size_t)(KT) * 64,                        &Bs[DB][      wave * 8][0]); \
    GLD(gB + (size_t) 64 * K_DIM + (size_t)(KT) * 64,  &Bs[DB][ 64 + wave * 8][0]); \
    GLD(gB + (size_t)128 * K_DIM + (size_t)(KT) * 64,  &Bs[DB][128 + wave * 8][0]); \
    GLD(gB + (size_t)192 * K_DIM + (size_t)(KT) * 64,  &Bs[DB][192 + wave * 8][0]); \
  } while (0)

#define VMCNT(n) asm volatile("s_waitcnt vmcnt(" #n ")" ::: "memory")
#define BAR() __builtin_amdgcn_s_barrier()

    bf16x8 fa[2][4], fb[2][2];   // two frag sets; all indices compile-time (no scratch)

#define LDA32(BUF, KK, I) (*(const bf16x8*)(&As[BUF][wm + (I) * 32 + l32][(((KK) * 2 + hi) ^ swz) * 8]))
#define LDB32(BUF, KK, J) (*(const bf16x8*)(&Bs[BUF][wn + (J) * 32 + l32][(((KK) * 2 + hi) ^ swz) * 8]))

#define READK(P, BUF, KK) do { \
    fa[P][0] = LDA32(BUF, KK, 0); fa[P][1] = LDA32(BUF, KK, 1); \
    fa[P][2] = LDA32(BUF, KK, 2); fa[P][3] = LDA32(BUF, KK, 3); \
    fb[P][0] = LDB32(BUF, KK, 0); fb[P][1] = LDB32(BUF, KK, 1); \
  } while (0)

#define MM(P) do { \
    __builtin_amdgcn_s_setprio(1); \
    _Pragma("unroll") \
    for (int i = 0; i < 4; ++i) { \
      acc[i][0] = __builtin_amdgcn_mfma_f32_32x32x16_bf16(fa[P][i], fb[P][0], acc[i][0], 0, 0, 0); \
      acc[i][1] = __builtin_amdgcn_mfma_f32_32x32x16_bf16(fa[P][i], fb[P][1], acc[i][1], 0, 0, 0); \
    } \
    __builtin_amdgcn_s_setprio(0); \
  } while (0)

// Standard tile on buf B_ (frag set 0 holds its kk0 on entry): stage tile KTN -> buf
// B_^1 during kk0/kk1; retire+publish at end-kk2; prefetch next tile's kk0 at kk3.
#define TILE_STD(B_, KTN) do { \
    READK(1, B_, 1);        STG_A4((B_) ^ 1, KTN); MM(0); \
    READK(0, B_, 2);        STG_B4((B_) ^ 1, KTN); MM(1); \
    READK(1, B_, 3);        MM(0); VMCNT(0); BAR(); \
    READK(0, (B_) ^ 1, 0);  MM(1); BAR(); \
  } while (0)

#define TILE_LAST(B_) do { \
    READK(1, B_, 1); MM(0); \
    READK(0, B_, 2); MM(1); \
    READK(1, B_, 3); MM(0); \
    MM(1); \
  } while (0)

    // Prologue: stage tile 0 -> buf0 (8 gloads/thread), drain, load kk0 frags.
    STG_A4(0, 0);
    STG_B4(0, 0);
    VMCNT(0);
    BAR();
    READK(0, 0, 0);

#pragma unroll 1
    for (int t = 0; t < NT - 2; t += 2) {
        TILE_STD(0, t + 1);   // compute tile t   (buf0), stage tile t+1 -> buf1
        TILE_STD(1, t + 2);   // compute tile t+1 (buf1), stage tile t+2 -> buf0
    }
    TILE_STD(0, NT - 1);      // tile 30 (buf0), stage tile 31 -> buf1
    TILE_LAST(1);             // tile 31 (buf1)

    // Epilogue: C/D layout col = lane&31, row = (r&3) + 8*(r>>2) + 4*hi
#pragma unroll
    for (int i = 0; i < 4; ++i) {
#pragma unroll
        for (int j = 0; j < 2; ++j) {
            const int col = n0 + wn + j * 32 + l32;
#pragma unroll
            for (int r = 0; r < 16; ++r) {
                const int row = m0 + wm + i * 32 + (r & 3) + 8 * (r >> 2) + 4 * hi;
                C[(size_t)row * N_DIM + col] = acc[i][j][r];
            }
        }
    }
}

extern "C" void kernel_launch(void* const* d_in, const int* in_sizes, int n_in,
                              void* d_out, int out_size, void* d_ws, size_t ws_size,
                              hipStream_t stream) {
    const float* x      = (const float*)d_in[0];
    const float* wfp8   = (const float*)d_in[1];
    const float* wscale = (const float*)d_in[2];
    float* out = (float*)d_out;

    unsigned short* xdq = (unsigned short*)d_ws;                    // M*K bf16
    unsigned short* wdq = xdq + (size_t)M_DIM * K_DIM;              // N*K bf16

    quant_all_kernel<<<XGRID + WGRID, 256, 0, stream>>>(x, xdq, wfp8, wscale, wdq);
    gemm_bt_kernel<<<dim3(M_DIM / BM, N_DIM / BN), 512, 0, stream>>>(xdq, wdq, out);
}

// Round 5
// 358.446 us; speedup vs baseline: 1.0621x; 1.0072x over previous
//
#include <hip/hip_runtime.h>

#define M_DIM 16384
#define N_DIM 2048
#define K_DIM 2048
#define KB    (K_DIM / 128)

// GEMM geometry: 256x256 tile, BK=64, 8 waves (2M x 4N), double-buffered 128 KiB LDS
#define BM 256
#define BN 256
#define BK 64
#define NT (K_DIM / BK)   // 32 K-tiles

// quant grid partition: 256 threads x 8 floats per block
#define XGRID (M_DIM * K_DIM / 2048)   // 16384
#define WGRID (N_DIM * K_DIM / 2048)   // 2048

typedef __bf16 bf16x8 __attribute__((ext_vector_type(8)));
typedef float  f32x4  __attribute__((ext_vector_type(4)));

__device__ __forceinline__ unsigned short f32_to_bf16_rne(float f) {
    unsigned int u = __float_as_uint(f);
    u += 0x7FFFu + ((u >> 16) & 1u);
    return (unsigned short)(u >> 16);
}

// ---- Fused pass: activation quant+dequant (blocks [0,XGRID)) and weight dequant ----
__global__ __launch_bounds__(256) void quant_all_kernel(const float* __restrict__ x,
                                                        unsigned short* __restrict__ xdq,
                                                        const float* __restrict__ w,
                                                        const float* __restrict__ wscale,
                                                        unsigned short* __restrict__ wdq) {
    const int tid = threadIdx.x;
    if (blockIdx.x < XGRID) {
        // 16 consecutive lanes cover one 128-elem K-block (8 floats each)
        const size_t base = ((size_t)blockIdx.x * 256 + tid) * 8;
        const float4 va = *(const float4*)(x + base);
        const float4 vb = *(const float4*)(x + base + 4);
        float amax = fmaxf(
            fmaxf(fmaxf(fabsf(va.x), fabsf(va.y)), fmaxf(fabsf(va.z), fabsf(va.w))),
            fmaxf(fmaxf(fabsf(vb.x), fabsf(vb.y)), fmaxf(fabsf(vb.z), fabsf(vb.w))));
#pragma unroll
        for (int m = 8; m >= 1; m >>= 1)
            amax = fmaxf(amax, __shfl_xor(amax, m, 64));
        float s = amax / 448.0f;                  // true f32 div (matches reference)
        if (s == 0.0f) s = 1.0f;
        const int p01 = __builtin_amdgcn_cvt_pk_fp8_f32(va.x / s, va.y / s, 0, false);
        const int p23 = __builtin_amdgcn_cvt_pk_fp8_f32(va.z / s, va.w / s, 0, false);
        const int p45 = __builtin_amdgcn_cvt_pk_fp8_f32(vb.x / s, vb.y / s, 0, false);
        const int p67 = __builtin_amdgcn_cvt_pk_fp8_f32(vb.z / s, vb.w / s, 0, false);
        uint4 out;
        out.x = (unsigned int)f32_to_bf16_rne(__builtin_amdgcn_cvt_f32_fp8(p01, 0) * s)
              | ((unsigned int)f32_to_bf16_rne(__builtin_amdgcn_cvt_f32_fp8(p01, 1) * s) << 16);
        out.y = (unsigned int)f32_to_bf16_rne(__builtin_amdgcn_cvt_f32_fp8(p23, 0) * s)
              | ((unsigned int)f32_to_bf16_rne(__builtin_amdgcn_cvt_f32_fp8(p23, 1) * s) << 16);
        out.z = (unsigned int)f32_to_bf16_rne(__builtin_amdgcn_cvt_f32_fp8(p45, 0) * s)
              | ((unsigned int)f32_to_bf16_rne(__builtin_amdgcn_cvt_f32_fp8(p45, 1) * s) << 16);
        out.w = (unsigned int)f32_to_bf16_rne(__builtin_amdgcn_cvt_f32_fp8(p67, 0) * s)
              | ((unsigned int)f32_to_bf16_rne(__builtin_amdgcn_cvt_f32_fp8(p67, 1) * s) << 16);
        *(uint4*)(xdq + base) = out;
    } else {
        const size_t e = ((size_t)(blockIdx.x - XGRID) * 256 + tid) * 8;
        const float4 va = *(const float4*)(w + e);
        const float4 vb = *(const float4*)(w + e + 4);
        const int n = (int)(e >> 11);
        const int k = (int)(e & 2047);
        const float s = wscale[(n >> 7) * KB + (k >> 7)];   // k..k+7 same 128-block
        uint4 out;
        out.x = (unsigned int)f32_to_bf16_rne(va.x * s) | ((unsigned int)f32_to_bf16_rne(va.y * s) << 16);
        out.y = (unsigned int)f32_to_bf16_rne(va.z * s) | ((unsigned int)f32_to_bf16_rne(va.w * s) << 16);
        out.z = (unsigned int)f32_to_bf16_rne(vb.x * s) | ((unsigned int)f32_to_bf16_rne(vb.y * s) << 16);
        out.w = (unsigned int)f32_to_bf16_rne(vb.z * s) | ((unsigned int)f32_to_bf16_rne(vb.w * s) << 16);
        *(uint4*)(wdq + e) = out;
    }
}

// ---- GEMM: C = A @ B^T, bf16 in, f32 out. 256x256 tile, m201-form 8-phase schedule ----
//
// LDS: As/Bs[buf][kh][256 rows][32 cols] — 64B rows (row parity shifts banks by 16):
// measured ZERO bank conflicts with pc = quad ^ ((l16>>1)&3) reads (rounds 1-3).
// Staging pre-swizzles the per-lane GLOBAL source chunk; gload dest stays lane-linear.
//
// 4 phases per K-tile, 16 MFMA each (quadrant = 4 i-rows x 4 j-cols), reads EVENED to
// 8/4/8/4 b128 per phase: bf[4] of a kh-panel is held across the two i-half phases.
// Phase form (m201): [reads; 2 stage gloads] BAR  asm lgkmcnt(0)+sched_barrier
// setprio(1) 16xMFMA setprio(0)  [counted vmcnt]  BAR.
//
// Staging ledger (2 gloads/phase, vmcnt NEVER drains in steady state; round-3 proven):
//   tile t: ph0: A-kh1(t+1)->buf^1   ph1: B-kh1(t+1)->buf^1
//           ph2: A-kh0(t+2)->buf     ph3: B-kh0(t+2)->buf
//   end-ph1 vmcnt(8) retires kh1(t) units (needed ph2; 8 younger in flight);
//   end-ph3 vmcnt(8) retires kh0(t+1) units (needed t+1 ph0; 8 younger in flight).
__global__ __launch_bounds__(512, 2) void gemm_bt_kernel(const unsigned short* __restrict__ A,
                                                         const unsigned short* __restrict__ B,
                                                         float* __restrict__ C) {
    __shared__ __align__(16) unsigned short As[2][2][256][32];   // 64 KiB
    __shared__ __align__(16) unsigned short Bs[2][2][256][32];   // 64 KiB

    const int tid  = threadIdx.x;
    const int lane = tid & 63;
    const int wave = tid >> 6;
    const int wm   = (wave >> 2) * 128;   // 2 waves along M
    const int wn   = (wave & 3) * 64;     // 4 waves along N
    const int quad = lane >> 4;
    const int l16  = lane & 15;
    const int pc   = quad ^ ((l16 >> 1) & 3);   // physical chunk within a kh-panel

    // grid: x carries M so same-x blocks (sharing the A-slab) land on one XCD
    const int m0 = blockIdx.x * BM;
    const int n0 = blockIdx.y * BN;

    f32x4 acc[8][4] = {};

    // Staging: lane row = tid>>2 (0..127), physical chunk tid&3; source chunk pre-swizzled.
    const int srow = tid >> 2;
    const int sc   = (tid & 3) ^ ((tid >> 3) & 3);   // (row>>1)&3 == (tid>>3)&3
    const unsigned short* gA = A + (size_t)(m0 + srow) * K_DIM + sc * 8;
    const unsigned short* gB = B + (size_t)(n0 + srow) * K_DIM + sc * 8;

#define GLD(SRC, DST) __builtin_amdgcn_global_load_lds( \
    (__attribute__((address_space(1))) void*)(SRC), \
    (__attribute__((address_space(3))) void*)(DST), 16, 0, 0)

#define STG_A(DB, KH, KT) do { \
    GLD(gA + (size_t)(KT) * 64 + (KH) * 32,                       &As[DB][KH][wave * 16][0]); \
    GLD(gA + (size_t)128 * K_DIM + (size_t)(KT) * 64 + (KH) * 32, &As[DB][KH][128 + wave * 16][0]); \
  } while (0)
#define STG_B(DB, KH, KT) do { \
    GLD(gB + (size_t)(KT) * 64 + (KH) * 32,                       &Bs[DB][KH][wave * 16][0]); \
    GLD(gB + (size_t)128 * K_DIM + (size_t)(KT) * 64 + (KH) * 32, &Bs[DB][KH][128 + wave * 16][0]); \
  } while (0)

#define VMCNT(n) asm volatile("s_waitcnt vmcnt(" #n ")" ::: "memory")
#define BAR() __builtin_amdgcn_s_barrier()
#define LGKM0() do { \
    asm volatile("s_waitcnt lgkmcnt(0)" ::: "memory"); \
    __builtin_amdgcn_sched_barrier(0); \
  } while (0)

#define LDA(BUF, KH, i) (*(const bf16x8*)(&As[BUF][KH][wm + (i) * 16 + l16][pc * 8]))
#define LDB(BUF, KH, j) (*(const bf16x8*)(&Bs[BUF][KH][wn + (j) * 16 + l16][pc * 8]))

// 16 MFMA: i-half I0..I0+3 x j 0..3
#define MM16(I0) do { \
    __builtin_amdgcn_s_setprio(1); \
    _Pragma("unroll") \
    for (int i = 0; i < 4; ++i) { \
      _Pragma("unroll") \
      for (int j = 0; j < 4; ++j) \
        acc[(I0) + i][j] = __builtin_amdgcn_mfma_f32_16x16x32_bf16(af[i], bf[j], acc[(I0) + i][j], 0, 0, 0); \
    } \
    __builtin_amdgcn_s_setprio(0); \
  } while (0)

// One K-tile = 4 phases (8/4/8/4 reads). S0..S3 staging per phase; W1/W3 counted waits.
#define TILE(BUF, S0, S1, S2, S3, W1, W3) do { \
    bf16x8 af[4], bf[4]; \
    af[0] = LDA(BUF, 0, 0); af[1] = LDA(BUF, 0, 1); af[2] = LDA(BUF, 0, 2); af[3] = LDA(BUF, 0, 3); \
    bf[0] = LDB(BUF, 0, 0); bf[1] = LDB(BUF, 0, 1); bf[2] = LDB(BUF, 0, 2); bf[3] = LDB(BUF, 0, 3); \
    S0; BAR(); LGKM0(); MM16(0); BAR(); \
    af[0] = LDA(BUF, 0, 4); af[1] = LDA(BUF, 0, 5); af[2] = LDA(BUF, 0, 6); af[3] = LDA(BUF, 0, 7); \
    S1; BAR(); LGKM0(); MM16(4); W1; BAR(); \
    af[0] = LDA(BUF, 1, 0); af[1] = LDA(BUF, 1, 1); af[2] = LDA(BUF, 1, 2); af[3] = LDA(BUF, 1, 3); \
    bf[0] = LDB(BUF, 1, 0); bf[1] = LDB(BUF, 1, 1); bf[2] = LDB(BUF, 1, 2); bf[3] = LDB(BUF, 1, 3); \
    S2; BAR(); LGKM0(); MM16(0); BAR(); \
    af[0] = LDA(BUF, 1, 4); af[1] = LDA(BUF, 1, 5); af[2] = LDA(BUF, 1, 6); af[3] = LDA(BUF, 1, 7); \
    S3; BAR(); LGKM0(); MM16(4); W3; BAR(); \
  } while (0)

    // Prologue: kh0(0), kh1(0) -> buf0; kh0(1) -> buf1 (12 gloads). vmcnt(8) retires
    // kh0(0) only; in-flight {kh1(0) x4, kh0(1) x4} matches the loop invariant.
    STG_A(0, 0, 0); STG_B(0, 0, 0);
    STG_A(0, 1, 0); STG_B(0, 1, 0);
    STG_A(1, 0, 1); STG_B(1, 0, 1);
    VMCNT(8);
    BAR();

#pragma unroll 1
    for (int t = 0; t < NT - 2; t += 2) {
        TILE(0, STG_A(1, 1, t + 1), STG_B(1, 1, t + 1),
                STG_A(0, 0, t + 2), STG_B(0, 0, t + 2), VMCNT(8), VMCNT(8));
        TILE(1, STG_A(0, 1, t + 2), STG_B(0, 1, t + 2),
                STG_A(1, 0, t + 3), STG_B(1, 0, t + 3), VMCNT(8), VMCNT(8));
    }
    // Tile 30 (buf0): stage only kh1(31); tile 31 (buf1): drain.
    TILE(0, STG_A(1, 1, NT - 1), STG_B(1, 1, NT - 1), (void)0, (void)0, VMCNT(8), VMCNT(4));
    TILE(1, (void)0, (void)0, (void)0, (void)0, VMCNT(0), (void)0);

    // C/D layout: row = quad*4 + reg, col = lane&15
#pragma unroll
    for (int i = 0; i < 8; ++i) {
        const int row = m0 + wm + i * 16 + quad * 4;
#pragma unroll
        for (int j = 0; j < 4; ++j) {
            const int col = n0 + wn + j * 16 + l16;
            float* cp = C + (size_t)row * N_DIM + col;
#pragma unroll
            for (int r = 0; r < 4; ++r)
                cp[(size_t)r * N_DIM] = acc[i][j][r];
        }
    }
}

extern "C" void kernel_launch(void* const* d_in, const int* in_sizes, int n_in,
                              void* d_out, int out_size, void* d_ws, size_t ws_size,
                              hipStream_t stream) {
    const float* x      = (const float*)d_in[0];
    const float* wfp8   = (const float*)d_in[1];
    const float* wscale = (const float*)d_in[2];
    float* out = (float*)d_out;

    unsigned short* xdq = (unsigned short*)d_ws;                    // M*K bf16
    unsigned short* wdq = xdq + (size_t)M_DIM * K_DIM;              // N*K bf16

    quant_all_kernel<<<XGRID + WGRID, 256, 0, stream>>>(x, xdq, wfp8, wscale, wdq);
    gemm_bt_kernel<<<dim3(M_DIM / BM, N_DIM / BN), 512, 0, stream>>>(xdq, wdq, out);
}

// Round 6
// 349.861 us; speedup vs baseline: 1.0882x; 1.0245x over previous
//
#include <hip/hip_runtime.h>

#define M_DIM 16384
#define N_DIM 2048
#define K_DIM 2048
#define KB    (K_DIM / 128)

// GEMM geometry: 256x256 tile, BK=64, 8 waves (2M x 4N), double-buffered 128 KiB LDS
#define BM 256
#define BN 256
#define BK 64
#define NT (K_DIM / BK)   // 32 K-tiles

// quant grid partition: 256 threads x 8 floats per block
#define XGRID (M_DIM * K_DIM / 2048)   // 16384
#define WGRID (N_DIM * K_DIM / 2048)   // 2048

typedef __bf16 bf16x8 __attribute__((ext_vector_type(8)));
typedef float  f32x4  __attribute__((ext_vector_type(4)));
typedef int    i32x4  __attribute__((ext_vector_type(4)));

__device__ __forceinline__ unsigned short f32_to_bf16_rne(float f) {
    unsigned int u = __float_as_uint(f);
    u += 0x7FFFu + ((u >> 16) & 1u);
    return (unsigned short)(u >> 16);
}

// ---- Fused pass: activation quant+dequant (blocks [0,XGRID)) and weight dequant ----
__global__ __launch_bounds__(256) void quant_all_kernel(const float* __restrict__ x,
                                                        unsigned short* __restrict__ xdq,
                                                        const float* __restrict__ w,
                                                        const float* __restrict__ wscale,
                                                        unsigned short* __restrict__ wdq) {
    const int tid = threadIdx.x;
    if (blockIdx.x < XGRID) {
        // 16 consecutive lanes cover one 128-elem K-block (8 floats each)
        const size_t base = ((size_t)blockIdx.x * 256 + tid) * 8;
        const float4 va = *(const float4*)(x + base);
        const float4 vb = *(const float4*)(x + base + 4);
        float amax = fmaxf(
            fmaxf(fmaxf(fabsf(va.x), fabsf(va.y)), fmaxf(fabsf(va.z), fabsf(va.w))),
            fmaxf(fmaxf(fabsf(vb.x), fabsf(vb.y)), fmaxf(fabsf(vb.z), fabsf(vb.w))));
#pragma unroll
        for (int m = 8; m >= 1; m >>= 1)
            amax = fmaxf(amax, __shfl_xor(amax, m, 64));
        float s = amax / 448.0f;                  // true f32 div (matches reference)
        if (s == 0.0f) s = 1.0f;
        const int p01 = __builtin_amdgcn_cvt_pk_fp8_f32(va.x / s, va.y / s, 0, false);
        const int p23 = __builtin_amdgcn_cvt_pk_fp8_f32(va.z / s, va.w / s, 0, false);
        const int p45 = __builtin_amdgcn_cvt_pk_fp8_f32(vb.x / s, vb.y / s, 0, false);
        const int p67 = __builtin_amdgcn_cvt_pk_fp8_f32(vb.z / s, vb.w / s, 0, false);
        uint4 out;
        out.x = (unsigned int)f32_to_bf16_rne(__builtin_amdgcn_cvt_f32_fp8(p01, 0) * s)
              | ((unsigned int)f32_to_bf16_rne(__builtin_amdgcn_cvt_f32_fp8(p01, 1) * s) << 16);
        out.y = (unsigned int)f32_to_bf16_rne(__builtin_amdgcn_cvt_f32_fp8(p23, 0) * s)
              | ((unsigned int)f32_to_bf16_rne(__builtin_amdgcn_cvt_f32_fp8(p23, 1) * s) << 16);
        out.z = (unsigned int)f32_to_bf16_rne(__builtin_amdgcn_cvt_f32_fp8(p45, 0) * s)
              | ((unsigned int)f32_to_bf16_rne(__builtin_amdgcn_cvt_f32_fp8(p45, 1) * s) << 16);
        out.w = (unsigned int)f32_to_bf16_rne(__builtin_amdgcn_cvt_f32_fp8(p67, 0) * s)
              | ((unsigned int)f32_to_bf16_rne(__builtin_amdgcn_cvt_f32_fp8(p67, 1) * s) << 16);
        *(uint4*)(xdq + base) = out;
    } else {
        const size_t e = ((size_t)(blockIdx.x - XGRID) * 256 + tid) * 8;
        const float4 va = *(const float4*)(w + e);
        const float4 vb = *(const float4*)(w + e + 4);
        const int n = (int)(e >> 11);
        const int k = (int)(e & 2047);
        const float s = wscale[(n >> 7) * KB + (k >> 7)];   // k..k+7 same 128-block
        uint4 out;
        out.x = (unsigned int)f32_to_bf16_rne(va.x * s) | ((unsigned int)f32_to_bf16_rne(va.y * s) << 16);
        out.y = (unsigned int)f32_to_bf16_rne(va.z * s) | ((unsigned int)f32_to_bf16_rne(va.w * s) << 16);
        out.z = (unsigned int)f32_to_bf16_rne(vb.x * s) | ((unsigned int)f32_to_bf16_rne(vb.y * s) << 16);
        out.w = (unsigned int)f32_to_bf16_rne(vb.z * s) | ((unsigned int)f32_to_bf16_rne(vb.w * s) << 16);
        *(uint4*)(wdq + e) = out;
    }
}

// ---- GEMM: C = A @ B^T, bf16 in, f32 out. 256x256 tile, software-pipelined phases ----
//
// LDS: As/Bs[buf][kh][256][32] — 64B rows, zero-conflict read swizzle pc = quad^((l16>>1)&3)
// (measured 0 SQ_LDS_BANK_CONFLICT, rounds 1-3/5). Staging pre-swizzles the per-lane
// GLOBAL source chunk; global_load_lds dest stays lane-linear.
//
// Phase p window: [asm ds_read x(4|8) for phase p+1] [2 stage gloads]
//                 [s_waitcnt lgkmcnt(4|8) + sched_barrier]  <- waits on phase p's reads
//                 [setprio1 16 MFMA setprio0] [counted vmcnt if due] [s_barrier]
// Reads always drain under MFMA. Fences moved one phase early vs round 5 so that ph3's
// window can prefetch the NEXT tile's first fragments (kh0 retired at end-ph2).
//
// Per-wave read windows of tile t (buf b):  issue at →  used by:
//   ph0: A[b][0] i4-7 (ax, 4)                           ph1 MFMA
//   ph1: A[b][1] i0-3 + B[b][1] (ao/bo, 8)              ph2 MFMA
//   ph2: A[b][1] i4-7 (ax, 4)                           ph3 MFMA
//   ph3: A[b^1][0] i0-3 + B[b^1][0] (ae/be, 8)          (t+1) ph0 MFMA
// lgkm counts (outstanding AFTER this window's issues, oldest retiring first):
//   ph0: 8 old + 4 new -> wait lgkmcnt(4); ph1: 4+8 -> (8); ph2: 8+4 -> (4); ph3: 4+8 -> (8).
//
// Staging ledger (per wave, 2 gloads/phase; issue order A-kh1(t+1)@p0, B-kh1(t+1)@p1,
// A-kh0(t+2)@p2, B-kh0(t+2)@p3; inventory entering any tile = 8 {kh1(t), kh0(t+1)}):
//   end-ph0: vmcnt(6)  [10 outstanding -> retires kh1(t), read from ph1 window]
//   end-ph2: vmcnt(6)  [8 outstanding -> retires kh0(t+1), read from ph3 window]
//   tile 30: no S2/S3, end-ph2 vmcnt(4); tile 31: no stages, end-ph0 vmcnt(0).
__global__ __launch_bounds__(512, 2) void gemm_bt_kernel(const unsigned short* __restrict__ A,
                                                         const unsigned short* __restrict__ B,
                                                         float* __restrict__ C) {
    __shared__ __align__(16) unsigned short As[2][2][256][32];   // 64 KiB
    __shared__ __align__(16) unsigned short Bs[2][2][256][32];   // 64 KiB

    const int tid  = threadIdx.x;
    const int lane = tid & 63;
    const int wave = tid >> 6;
    const int wm   = (wave >> 2) * 128;   // 2 waves along M
    const int wn   = (wave & 3) * 64;     // 4 waves along N
    const int quad = lane >> 4;
    const int l16  = lane & 15;
    const int pc   = quad ^ ((l16 >> 1) & 3);   // physical chunk within a kh-panel

    // grid: x carries M so XCD round-robin partitions A-slabs
    const int m0 = blockIdx.x * BM;
    const int n0 = blockIdx.y * BN;

    f32x4 acc[8][4] = {};

    // Staging: lane row = tid>>2 (0..127), physical chunk tid&3; source chunk pre-swizzled.
    const int srow = tid >> 2;
    const int sc   = (tid & 3) ^ ((tid >> 3) & 3);   // (row>>1)&3 == (tid>>3)&3
    const unsigned short* gA = A + (size_t)(m0 + srow) * K_DIM + sc * 8;
    const unsigned short* gB = B + (size_t)(n0 + srow) * K_DIM + sc * 8;

#define GLD(SRC, DST) __builtin_amdgcn_global_load_lds( \
    (__attribute__((address_space(1))) void*)(SRC), \
    (__attribute__((address_space(3))) void*)(DST), 16, 0, 0)

#define STG_A(DB, KH, KT) do { \
    GLD(gA + (size_t)(KT) * 64 + (KH) * 32,                       &As[DB][KH][wave * 16][0]); \
    GLD(gA + (size_t)128 * K_DIM + (size_t)(KT) * 64 + (KH) * 32, &As[DB][KH][128 + wave * 16][0]); \
  } while (0)
#define STG_B(DB, KH, KT) do { \
    GLD(gB + (size_t)(KT) * 64 + (KH) * 32,                       &Bs[DB][KH][wave * 16][0]); \
    GLD(gB + (size_t)128 * K_DIM + (size_t)(KT) * 64 + (KH) * 32, &Bs[DB][KH][128 + wave * 16][0]); \
  } while (0)

#define VMCNT(n) asm volatile("s_waitcnt vmcnt(" #n ")" ::: "memory")
#define BAR() __builtin_amdgcn_s_barrier()
// Counted LDS wait + full scheduling fence (rule-18: MFMA must not hoist above the wait)
#define LGKM(n) do { \
    asm volatile("s_waitcnt lgkmcnt(" #n ")" ::: "memory"); \
    __builtin_amdgcn_sched_barrier(0); \
  } while (0)

    // Fragment registers (asm-written; indices all static)
    i32x4 ae0, ae1, ae2, ae3, be0, be1, be2, be3;   // kh-even A i0-3 + B
    i32x4 ao0, ao1, ao2, ao3, bo0, bo1, bo2, bo3;   // kh-odd  A i0-3 + B
    i32x4 ax0, ax1, ax2, ax3;                       // current A i4-7 (time-shared)

    // Base byte addresses in LDS (include row=(w*+l16), chunk pc); imm offsets add
    // BUF*32768 + KH*16384 + i*1024 (max 56320 < 64K).
    const unsigned aA = (unsigned)(unsigned long long)
        (__attribute__((address_space(3))) const void*)&As[0][0][wm + l16][pc * 8];
    const unsigned aB = (unsigned)(unsigned long long)
        (__attribute__((address_space(3))) const void*)&Bs[0][0][wn + l16][pc * 8];

#define DSR(D, BASE, IMM) \
    asm volatile("ds_read_b128 %0, %1 offset:%c2" : "=v"(D) : "v"(BASE), "i"(IMM))

#define RD_AX(BUF, KH) do { \
    DSR(ax0, aA, (BUF) * 32768 + (KH) * 16384 + 4096); \
    DSR(ax1, aA, (BUF) * 32768 + (KH) * 16384 + 5120); \
    DSR(ax2, aA, (BUF) * 32768 + (KH) * 16384 + 6144); \
    DSR(ax3, aA, (BUF) * 32768 + (KH) * 16384 + 7168); \
  } while (0)
#define RD_E(BUF, KH) do { \
    DSR(ae0, aA, (BUF) * 32768 + (KH) * 16384 + 0);    \
    DSR(ae1, aA, (BUF) * 32768 + (KH) * 16384 + 1024); \
    DSR(ae2, aA, (BUF) * 32768 + (KH) * 16384 + 2048); \
    DSR(ae3, aA, (BUF) * 32768 + (KH) * 16384 + 3072); \
    DSR(be0, aB, (BUF) * 32768 + (KH) * 16384 + 0);    \
    DSR(be1, aB, (BUF) * 32768 + (KH) * 16384 + 1024); \
    DSR(be2, aB, (BUF) * 32768 + (KH) * 16384 + 2048); \
    DSR(be3, aB, (BUF) * 32768 + (KH) * 16384 + 3072); \
  } while (0)
#define RD_O(BUF, KH) do { \
    DSR(ao0, aA, (BUF) * 32768 + (KH) * 16384 + 0);    \
    DSR(ao1, aA, (BUF) * 32768 + (KH) * 16384 + 1024); \
    DSR(ao2, aA, (BUF) * 32768 + (KH) * 16384 + 2048); \
    DSR(ao3, aA, (BUF) * 32768 + (KH) * 16384 + 3072); \
    DSR(bo0, aB, (BUF) * 32768 + (KH) * 16384 + 0);    \
    DSR(bo1, aB, (BUF) * 32768 + (KH) * 16384 + 1024); \
    DSR(bo2, aB, (BUF) * 32768 + (KH) * 16384 + 2048); \
    DSR(bo3, aB, (BUF) * 32768 + (KH) * 16384 + 3072); \
  } while (0)

#define BC(X) __builtin_bit_cast(bf16x8, X)
#define MMROW(I, AF, B0, B1, B2, B3) do { \
    acc[I][0] = __builtin_amdgcn_mfma_f32_16x16x32_bf16(BC(AF), BC(B0), acc[I][0], 0, 0, 0); \
    acc[I][1] = __builtin_amdgcn_mfma_f32_16x16x32_bf16(BC(AF), BC(B1), acc[I][1], 0, 0, 0); \
    acc[I][2] = __builtin_amdgcn_mfma_f32_16x16x32_bf16(BC(AF), BC(B2), acc[I][2], 0, 0, 0); \
    acc[I][3] = __builtin_amdgcn_mfma_f32_16x16x32_bf16(BC(AF), BC(B3), acc[I][3], 0, 0, 0); \
  } while (0)
#define MM16(I0, A0, A1, A2, A3, B0, B1, B2, B3) do { \
    __builtin_amdgcn_s_setprio(1); \
    MMROW((I0) + 0, A0, B0, B1, B2, B3); \
    MMROW((I0) + 1, A1, B0, B1, B2, B3); \
    MMROW((I0) + 2, A2, B0, B1, B2, B3); \
    MMROW((I0) + 3, A3, B0, B1, B2, B3); \
    __builtin_amdgcn_s_setprio(0); \
  } while (0)

// One steady K-tile on buf B_ (literal), staging kh1(KT1)->B_^1 and kh0(KT2)->B_.
#define TILE_STD(B_, KT1, KT2) do { \
    RD_AX(B_, 0);      STG_A((B_) ^ 1, 1, KT1); LGKM(4); MM16(0, ae0, ae1, ae2, ae3, be0, be1, be2, be3); VMCNT(6); BAR(); \
    RD_O(B_, 1);       STG_B((B_) ^ 1, 1, KT1); LGKM(8); MM16(4, ax0, ax1, ax2, ax3, be0, be1, be2, be3); BAR(); \
    RD_AX(B_, 1);      STG_A(B_, 0, KT2);       LGKM(4); MM16(0, ao0, ao1, ao2, ao3, bo0, bo1, bo2, bo3); VMCNT(6); BAR(); \
    RD_E((B_) ^ 1, 0); STG_B(B_, 0, KT2);       LGKM(8); MM16(4, ax0, ax1, ax2, ax3, bo0, bo1, bo2, bo3); BAR(); \
  } while (0)

    // Prologue: kh0(0), kh1(0) -> buf0; kh0(1) -> buf1 (12 gloads, steady issue order).
    // vmcnt(8) retires kh0(0); inventory {kh1(0) x4, kh0(1) x4} = steady tile-entry state.
    STG_A(0, 0, 0); STG_B(0, 0, 0);
    STG_A(0, 1, 0); STG_B(0, 1, 0);
    STG_A(1, 0, 1); STG_B(1, 0, 1);
    VMCNT(8);
    BAR();
    RD_E(0, 0);   // tile 0 ph0 fragments (8 reads in flight = steady invariant)

#pragma unroll 1
    for (int t = 0; t < NT - 2; t += 2) {
        TILE_STD(0, t + 1, t + 2);   // tiles 0..29: buf0 tile stages kh1(t+1), kh0(t+2)
        TILE_STD(1, t + 2, t + 3);
    }
    // Tile 30 (buf0): stage only kh1(31); end-ph2 fence becomes vmcnt(4).
    RD_AX(0, 0); STG_A(1, 1, NT - 1); LGKM(4); MM16(0, ae0, ae1, ae2, ae3, be0, be1, be2, be3); VMCNT(6); BAR();
    RD_O(0, 1);  STG_B(1, 1, NT - 1); LGKM(8); MM16(4, ax0, ax1, ax2, ax3, be0, be1, be2, be3); BAR();
    RD_AX(0, 1);                      LGKM(4); MM16(0, ao0, ao1, ao2, ao3, bo0, bo1, bo2, bo3); VMCNT(4); BAR();
    RD_E(1, 0);                       LGKM(8); MM16(4, ax0, ax1, ax2, ax3, bo0, bo1, bo2, bo3); BAR();
    // Tile 31 (buf1): drain (no staging; retire kh1(31) at end-ph0).
    RD_AX(1, 0);                      LGKM(4); MM16(0, ae0, ae1, ae2, ae3, be0, be1, be2, be3); VMCNT(0); BAR();
    RD_O(1, 1);                       LGKM(8); MM16(4, ax0, ax1, ax2, ax3, be0, be1, be2, be3); BAR();
    RD_AX(1, 1);                      LGKM(4); MM16(0, ao0, ao1, ao2, ao3, bo0, bo1, bo2, bo3); BAR();
                                      LGKM(0); MM16(4, ax0, ax1, ax2, ax3, bo0, bo1, bo2, bo3);

    // C/D layout: row = quad*4 + reg, col = lane&15
#pragma unroll
    for (int i = 0; i < 8; ++i) {
        const int row = m0 + wm + i * 16 + quad * 4;
#pragma unroll
        for (int j = 0; j < 4; ++j) {
            const int col = n0 + wn + j * 16 + l16;
            float* cp = C + (size_t)row * N_DIM + col;
#pragma unroll
            for (int r = 0; r < 4; ++r)
                cp[(size_t)r * N_DIM] = acc[i][j][r];
        }
    }
}

extern "C" void kernel_launch(void* const* d_in, const int* in_sizes, int n_in,
                              void* d_out, int out_size, void* d_ws, size_t ws_size,
                              hipStream_t stream) {
    const float* x      = (const float*)d_in[0];
    const float* wfp8   = (const float*)d_in[1];
    const float* wscale = (const float*)d_in[2];
    float* out = (float*)d_out;

    unsigned short* xdq = (unsigned short*)d_ws;                    // M*K bf16
    unsigned short* wdq = xdq + (size_t)M_DIM * K_DIM;              // N*K bf16

    quant_all_kernel<<<XGRID + WGRID, 256, 0, stream>>>(x, xdq, wfp8, wscale, wdq);
    gemm_bt_kernel<<<dim3(M_DIM / BM, N_DIM / BN), 512, 0, stream>>>(xdq, wdq, out);
}